// Round 2
// baseline (576.681 us; speedup 1.0000x reference)
//
#include <hip/hip_runtime.h>

// BlockTopK sparsify, fully-coalesced version.
// Each lane owns ONE float4 (= half of an 8-float block). Lane pairs
// (2j, 2j+1) share a block; partner scores are exchanged with
// __shfl_xor(...,1) (DPP quad-perm, register-only). All global loads and
// stores are 16 B/lane contiguous -> 1 KiB per wave instruction, the same
// pattern as the 6.3 TB/s float4-copy ceiling.
//
// Tie-break (stable ascending argsort drops first 4):
//   element j precedes i iff s_j < s_i, or s_j == s_i and j < i.
// Lower lane (indices 0..3): all partner indices are larger  -> strict <.
// Upper lane (indices 4..7): all partner indices are smaller -> <=.

__device__ __forceinline__ float4 topk_half(float4 s, float4 xv, bool upper) {
    float4 t;
    t.x = __shfl_xor(s.x, 1);
    t.y = __shfl_xor(s.y, 1);
    t.z = __shfl_xor(s.z, 1);
    t.w = __shfl_xor(s.w, 1);

    float ss[4] = {s.x, s.y, s.z, s.w};
    float tt[4] = {t.x, t.y, t.z, t.w};
    float xx[4] = {xv.x, xv.y, xv.z, xv.w};
    float oo[4];

#pragma unroll
    for (int i = 0; i < 4; ++i) {
        int rank = 0;
#pragma unroll
        for (int j = 0; j < 4; ++j) {
            // own half: global indices share the same offset, tie-break on j<i
            rank += (ss[j] < ss[i]) || ((ss[j] == ss[i]) && (j < i));
            // partner half: predication instead of branch
            rank += (tt[j] < ss[i]) || (upper && (tt[j] == ss[i]));
        }
        oo[i] = (rank >= 4) ? xx[i] : 0.0f;
    }
    return make_float4(oo[0], oo[1], oo[2], oo[3]);
}

__global__ __launch_bounds__(256) void sparsify_topk_kernel(
    const float4* __restrict__ x4,
    const float4* __restrict__ s4,
    float4* __restrict__ o4,
    int nf)  // total number of float4s
{
    // Each workgroup handles 512 contiguous float4s: tid and tid+256.
    int f0 = blockIdx.x * 512 + threadIdx.x;
    int f1 = f0 + 256;
    bool upper = (threadIdx.x & 1);

    if (f1 < nf) {
        // fast path: all 4 loads issued before any compute (ILP)
        float4 s0 = s4[f0];
        float4 x0 = x4[f0];
        float4 s1 = s4[f1];
        float4 x1 = x4[f1];
        o4[f0] = topk_half(s0, x0, upper);
        o4[f1] = topk_half(s1, x1, upper);
    } else {
        if (f0 < nf) o4[f0] = topk_half(s4[f0], x4[f0], upper);
        if (f1 < nf) o4[f1] = topk_half(s4[f1], x4[f1], upper);
    }
}

extern "C" void kernel_launch(void* const* d_in, const int* in_sizes, int n_in,
                              void* d_out, int out_size, void* d_ws, size_t ws_size,
                              hipStream_t stream) {
    const float4* x4 = (const float4*)d_in[0];
    const float4* s4 = (const float4*)d_in[1];
    float4* o4 = (float4*)d_out;

    int n = in_sizes[0];      // 8192*8192 = 67,108,864 floats
    int nf = n / 4;           // 16,777,216 float4s
    int grid = (nf + 511) / 512;  // 32768 workgroups of 256 threads, 2 f4/thread

    sparsify_topk_kernel<<<grid, 256, 0, stream>>>(x4, s4, o4, nf);
}